// Round 3
// baseline (105.210 us; speedup 1.0000x reference)
//
#include <hip/hip_runtime.h>

#define N_ 256
#define E_ 32640

typedef __bf16 bf16x8 __attribute__((ext_vector_type(8)));
typedef unsigned short u16x8 __attribute__((ext_vector_type(8)));
typedef float f32x4 __attribute__((ext_vector_type(4)));

__device__ __forceinline__ unsigned short cvt_bf16(float f) {
  unsigned u = __float_as_uint(f);
  u = (u + 0x7FFFu + ((u >> 16) & 1u)) >> 16;
  return (unsigned short)u;
}

// Swizzled LDS helpers: row-major bf16, byte ^= (row&7)<<4
__device__ __forceinline__ bf16x8 ldfrag(const unsigned short* base, int row, int kbyte, int rowbytes) {
  int byte = (row * rowbytes + kbyte) ^ ((row & 7) << 4);
  return *reinterpret_cast<const bf16x8*>(reinterpret_cast<const char*>(base) + byte);
}

__device__ __forceinline__ void st2(unsigned short* base, int row, int colbyte, int rowbytes, unsigned short v) {
  int byte = (row * rowbytes + colbyte) ^ ((row & 7) << 4);
  *reinterpret_cast<unsigned short*>(reinterpret_cast<char*>(base) + byte) = v;
}

__device__ __forceinline__ bf16x8 pack8(float4 lo, float4 hi) {
  u16x8 u;
  u[0] = cvt_bf16(lo.x); u[1] = cvt_bf16(lo.y); u[2] = cvt_bf16(lo.z); u[3] = cvt_bf16(lo.w);
  u[4] = cvt_bf16(hi.x); u[5] = cvt_bf16(hi.y); u[6] = cvt_bf16(hi.z); u[7] = cvt_bf16(hi.w);
  return __builtin_bit_cast(bf16x8, u);
}

// One block = one (batch, 32-row chunk). 512 threads = 8 waves.
__global__ __launch_bounds__(512, 4) void chunk_kernel(
    const float* __restrict__ se_g,
    const float* __restrict__ w1,  const float* __restrict__ b1,
    const float* __restrict__ w2,  const float* __restrict__ b2,
    const float* __restrict__ wo1, const float* __restrict__ bo1,
    const float* __restrict__ wo2, const float* __restrict__ bo2,
    float* __restrict__ ws)
{
  __shared__ __align__(16) unsigned short sA[3][32 * N_]; // 3x[32][256] bf16  48 KB (rowbytes 512)
  __shared__ __align__(16) unsigned short sH[32 * 128];   // 8 KB; overlay X@0, P@+4096B
  __shared__ __align__(16) unsigned short sWO1[64 * 64];  // 8 KB (rowbytes 128)
  __shared__ __align__(16) unsigned short sWO2[64 * 64];  // 8 KB
  __shared__ float sB1[128], sB2[64], sBO1[64], sBO2[64];
  __shared__ float sAccW[8][64];

  const int tid = threadIdx.x;
  const int i   = blockIdx.x;
  // XCD-aware decode: all 8 chunks of a batch share i%8 -> same XCD (round-robin heuristic)
  const int batch = (i & 7) * 32 + ((i >> 3) & 31);
  const int chunk = i >> 8;
  const int r0    = chunk * 32;

  const int w   = tid >> 6;   // wave 0..7
  const int l   = tid & 63;
  const int l15 = l & 15;
  const int lk  = l >> 4;     // 0..3
  const int kb0 = lk * 16;

  const int c1 = w;           // GEMM1 col-tile (of 8); row-tiles 0 and 1
  const int r2 = w >> 2;      // GEMM2/head row-tile (of 2)
  const int c2 = w & 3;       // GEMM2/head col-tile (of 4)

  // ---- W1/W2 B-fragments -> registers (per-wave col-tile, reused 3e x 2 rowtiles) ----
  bf16x8 W1f[8];
  {
    const float* p = w1 + (c1 * 16 + l15) * 256 + lk * 8;
    #pragma unroll
    for (int ks = 0; ks < 8; ++ks) {
      float4 lo = *reinterpret_cast<const float4*>(p + ks * 32);
      float4 hi = *reinterpret_cast<const float4*>(p + ks * 32 + 4);
      W1f[ks] = pack8(lo, hi);
    }
  }
  bf16x8 W2f[4];
  {
    const float* p = w2 + (c2 * 16 + l15) * 128 + lk * 8;
    #pragma unroll
    for (int ks = 0; ks < 4; ++ks) {
      float4 lo = *reinterpret_cast<const float4*>(p + ks * 32);
      float4 hi = *reinterpret_cast<const float4*>(p + ks * 32 + 4);
      W2f[ks] = pack8(lo, hi);
    }
  }

  // ---- stage WO1/WO2 bf16 swizzled (rowbytes 128) + biases ----
  for (int t = tid; t < 1024; t += 512) {
    int idx = t << 2;
    int row = idx >> 6;
    int byte = (idx * 2) ^ ((row & 7) << 4);
    {
      const float4 v = *reinterpret_cast<const float4*>(wo1 + idx);
      ushort4 u = make_ushort4(cvt_bf16(v.x), cvt_bf16(v.y), cvt_bf16(v.z), cvt_bf16(v.w));
      *reinterpret_cast<ushort4*>(reinterpret_cast<char*>(sWO1) + byte) = u;
    }
    {
      const float4 v = *reinterpret_cast<const float4*>(wo2 + idx);
      ushort4 u = make_ushort4(cvt_bf16(v.x), cvt_bf16(v.y), cvt_bf16(v.z), cvt_bf16(v.w));
      *reinterpret_cast<ushort4*>(reinterpret_cast<char*>(sWO2) + byte) = u;
    }
  }
  if (tid < 128) sB1[tid] = b1[tid];
  if (tid < 64)  { sB2[tid] = b2[tid]; sBO1[tid] = bo1[tid]; sBO2[tid] = bo2[tid]; }
  reinterpret_cast<float*>(sAccW)[tid] = 0.f;   // 8*64 = 512 floats
  // (sync below covers staging too)

  const float4* seB = reinterpret_cast<const float4*>(se_g) + (size_t)batch * E_;
  unsigned short* sX = sH;
  unsigned short* sP = sH + 32 * 64;  // +4096 B

  // ---- stage 3 A-chunks [32][256] bf16 from sparse_edges ----
  // (a) upper triangle: row-contiguous float4 reads
  #pragma unroll
  for (int rr = 0; rr < 4; ++rr) {
    int lr = (w << 2) + rr;          // local row 0..31
    int gi = r0 + lr;
    int cnt = 255 - gi;
    int ubase = gi * 255 - ((gi * (gi - 1)) >> 1);
    for (int jj = l; jj < cnt; jj += 64) {
      float4 v = seB[ubase + jj];
      int cb = (gi + 1 + jj) * 2;
      st2(sA[0], lr, cb, 512, cvt_bf16(v.y));
      st2(sA[1], lr, cb, 512, cvt_bf16(v.z));
      st2(sA[2], lr, cb, 512, cvt_bf16(v.w));
    }
  }
  // (b) lower triangle via column strips: for fixed j, u(j,i) contiguous in i
  {
    int sub = tid >> 5, l32 = tid & 31;
    for (int j = sub; j < r0 + 31; j += 16) {
      int i0  = (j + 1 > r0) ? (j + 1) : r0;
      int cnt = r0 + 32 - i0;
      if (l32 < cnt) {
        int ii = i0 + l32;
        int u = j * 255 - ((j * (j - 1)) >> 1) + (ii - j - 1);
        float4 v = seB[u];
        int lr = ii - r0, cb = j * 2;
        st2(sA[0], lr, cb, 512, cvt_bf16(v.y));
        st2(sA[1], lr, cb, 512, cvt_bf16(v.z));
        st2(sA[2], lr, cb, 512, cvt_bf16(v.w));
      }
    }
  }
  // diagonal = 0
  if (tid < 32) {
    int cb = (r0 + tid) * 2;
    st2(sA[0], tid, cb, 512, 0);
    st2(sA[1], tid, cb, 512, 0);
    st2(sA[2], tid, cb, 512, 0);
  }
  __syncthreads();

  f32x4 outAcc = {0.f, 0.f, 0.f, 0.f};

  for (int e = 0; e < 3; ++e) {
    // GEMM1: H[32][128] = relu(A @ W1^T + b1); wave: col-tile c1, row-tiles 0,1
    {
      f32x4 acc0 = {0,0,0,0}, acc1 = {0,0,0,0};
      const unsigned short* sAe = sA[e];
      #pragma unroll
      for (int ks = 0; ks < 8; ++ks) {
        int kb = ks * 64 + kb0;
        bf16x8 a0 = ldfrag(sAe, l15,      kb, 512);
        bf16x8 a1 = ldfrag(sAe, 16 + l15, kb, 512);
        acc0 = __builtin_amdgcn_mfma_f32_16x16x32_bf16(a0, W1f[ks], acc0, 0, 0, 0);
        acc1 = __builtin_amdgcn_mfma_f32_16x16x32_bf16(a1, W1f[ks], acc1, 0, 0, 0);
      }
      int cc = c1 * 16 + l15;
      float bias = sB1[cc];
      #pragma unroll
      for (int r = 0; r < 4; ++r) {
        st2(sH, lk * 4 + r,      cc * 2, 256, cvt_bf16(fmaxf(acc0[r] + bias, 0.f)));
        st2(sH, 16 + lk * 4 + r, cc * 2, 256, cvt_bf16(fmaxf(acc1[r] + bias, 0.f)));
      }
    }
    __syncthreads();
    // GEMM2: M[32][64] = relu(H @ W2^T + b2); weighted accumulate; tile (r2,c2)
    {
      f32x4 acc = {0,0,0,0};
      int arow = r2 * 16 + l15;
      #pragma unroll
      for (int ks = 0; ks < 4; ++ks) {
        bf16x8 a = ldfrag(sH, arow, ks * 64 + kb0, 256);
        acc = __builtin_amdgcn_mfma_f32_16x16x32_bf16(a, W2f[ks], acc, 0, 0, 0);
      }
      float bias = sB2[c2 * 16 + l15];
      float wte  = 0.2f * (float)(e + 1);
      #pragma unroll
      for (int r = 0; r < 4; ++r)
        outAcc[r] += wte * fmaxf(acc[r] + bias, 0.f);
    }
    __syncthreads();  // before next e overwrites sH
  }

  // ---- head: X[32][64] -> P1 -> P2 -> row sums ----
  {
    int col = c2 * 16 + l15;
    #pragma unroll
    for (int r = 0; r < 4; ++r)
      st2(sX, r2 * 16 + lk * 4 + r, col * 2, 128, cvt_bf16(outAcc[r]));
  }
  __syncthreads();
  {
    f32x4 acc = {0,0,0,0};
    int arow = r2 * 16 + l15;
    int brow = c2 * 16 + l15;
    #pragma unroll
    for (int ks = 0; ks < 2; ++ks) {
      bf16x8 a  = ldfrag(sX,   arow, ks * 64 + kb0, 128);
      bf16x8 bb = ldfrag(sWO1, brow, ks * 64 + kb0, 128);
      acc = __builtin_amdgcn_mfma_f32_16x16x32_bf16(a, bb, acc, 0, 0, 0);
    }
    float bias = sBO1[c2 * 16 + l15];
    #pragma unroll
    for (int r = 0; r < 4; ++r)
      st2(sP, r2 * 16 + lk * 4 + r, (c2 * 16 + l15) * 2, 128, cvt_bf16(fmaxf(acc[r] + bias, 0.f)));
  }
  __syncthreads();
  {
    f32x4 acc = {0,0,0,0};
    int arow = r2 * 16 + l15;
    int brow = c2 * 16 + l15;
    #pragma unroll
    for (int ks = 0; ks < 2; ++ks) {
      bf16x8 a  = ldfrag(sP,   arow, ks * 64 + kb0, 128);
      bf16x8 bb = ldfrag(sWO2, brow, ks * 64 + kb0, 128);
      acc = __builtin_amdgcn_mfma_f32_16x16x32_bf16(a, bb, acc, 0, 0, 0);
    }
    float bias = sBO2[c2 * 16 + l15];
    float s = 0.f;
    #pragma unroll
    for (int r = 0; r < 4; ++r) s += fmaxf(acc[r] + bias, 0.f);
    s += __shfl_xor(s, 16);
    s += __shfl_xor(s, 32);
    if (lk == 0) sAccW[w][c2 * 16 + l15] = s;  // row-tile r2's col sums
  }
  __syncthreads();

  if (tid < 64) {
    float s = 0.f;
    #pragma unroll
    for (int ww = 0; ww < 8; ++ww) s += sAccW[ww][tid];
    ws[((size_t)batch * 8 + chunk) * 64 + tid] = s;
  }
}

// Per batch: sum 8 chunk partials, mean over 256 atoms, project 64->2.
__global__ __launch_bounds__(64) void finish_kernel(
    const float* __restrict__ ws,
    const float* __restrict__ wo3, const float* __restrict__ bo3,
    float* __restrict__ out)
{
  int b = blockIdx.x;
  int l = threadIdx.x;
  float s = 0.f;
  #pragma unroll
  for (int c = 0; c < 8; ++c) s += ws[((size_t)b * 8 + c) * 64 + l];
  s *= (1.0f / 256.0f);
  float v0 = s * wo3[l];
  float v1 = s * wo3[64 + l];
  #pragma unroll
  for (int off = 32; off > 0; off >>= 1) {
    v0 += __shfl_down(v0, off);
    v1 += __shfl_down(v1, off);
  }
  if (l == 0) {
    out[b * 2 + 0] = v0 + bo3[0];
    out[b * 2 + 1] = v1 + bo3[1];
  }
}

extern "C" void kernel_launch(void* const* d_in, const int* in_sizes, int n_in,
                              void* d_out, int out_size, void* d_ws, size_t ws_size,
                              hipStream_t stream) {
  (void)in_sizes; (void)n_in; (void)ws_size; (void)out_size;
  const float* se  = (const float*)d_in[1];   // d_in[0] = `inputs` — shape-only, never read
  const float* w1  = (const float*)d_in[2];
  const float* b1  = (const float*)d_in[3];
  const float* w2  = (const float*)d_in[4];
  const float* b2  = (const float*)d_in[5];
  const float* wo1 = (const float*)d_in[6];
  const float* bo1 = (const float*)d_in[7];
  const float* wo2 = (const float*)d_in[8];
  const float* bo2 = (const float*)d_in[9];
  const float* wo3 = (const float*)d_in[10];
  const float* bo3 = (const float*)d_in[11];
  float* ws = (float*)d_ws;                   // 2048 * 64 floats = 512 KB
  chunk_kernel<<<dim3(2048), dim3(512), 0, stream>>>(
      se, w1, b1, w2, b2, wo1, bo1, wo2, bo2, ws);
  finish_kernel<<<dim3(256), dim3(64), 0, stream>>>(ws, wo3, bo3, (float*)d_out);
}